// Round 5
// baseline (100.020 us; speedup 1.0000x reference)
//
#include <hip/hip_runtime.h>

#define NROWS 256
#define ROWLEN 65536
#define TPB 1024
#define LOSS_IDX ((size_t)NROWS * (size_t)ROWLEN)

// XOR swizzle: bijective involution within each 1024-float block; spreads the
// stride-2C chunked accesses across banks. Applied to EVERY access of buf[].
__device__ __forceinline__ int SW(int i) { return i ^ ((i >> 5) & 31); }

// Force a wave-uniform float into an SGPR (filter taps): frees VGPRs.
__device__ __forceinline__ float rfl(float x) {
    union { float f; int i; } u; u.f = x;
    u.i = __builtin_amdgcn_readfirstlane(u.i);
    return u.f;
}

__device__ __forceinline__ float sigm(float z) { return 1.0f / (1.0f + __expf(-z)); }

__device__ __forceinline__ float hthr(float v, float a, float bp, float bm) {
    return v * (sigm(a * (v - bp)) + sigm(-a * (v + bm)));
}

// Intra-wave "barrier": valid only when producer and consumer lanes are in the
// SAME wave (deep levels run entirely in wave 0).
__device__ __forceinline__ void wave_sync() {
    __builtin_amdgcn_wave_barrier();
    __threadfence_block();
    __builtin_amdgcn_wave_barrier();
}

__device__ __forceinline__ void ldf_fwd(const float* sc, const float* rec, int lvl,
                                        float* sf, float* wv) {
    #pragma unroll
    for (int i = 0; i < 8; ++i) sf[i] = rfl(sc[lvl * 8 + i]);
    #pragma unroll
    for (int i = 0; i < 8; ++i) {
        float r = rfl(rec[lvl * 8 + 7 - i]);
        wv[i] = (i & 1) ? -r : r;            // _compute_wavelet
    }
}

__device__ __forceinline__ void ldf_rec(const float* sc, const float* rec, int lvl,
                                        float* sf, float* ws) {
    #pragma unroll
    for (int i = 0; i < 8; ++i) sf[i] = rfl(sc[lvl * 8 + i]);
    #pragma unroll
    for (int i = 0; i < 8; ++i) {
        float r = rfl(rec[lvl * 8 + 7 - i]);
        ws[i] = (i & 1) ? r : -r;            // _compute_wavelet_synthesis
    }
}

// Forward lifting level, fully in LDS: approx buf[0:2M) -> approx buf[0:M),
// thresholded detail -> buf[M:2M). Register-staged halo breaks the WAR.
template<int C, bool WAVE>
__device__ __forceinline__ void fwd_level(float* __restrict__ buf, int M, int tid,
                                          const float* sf, const float* wv,
                                          float a, float bp, float bm, float& loss)
{
    const int c0 = tid * C;          // C == M / nthreads exactly -> all active
    float ev[C + 7], od[C + 7];
    #pragma unroll
    for (int j = 0; j < C + 7; ++j) {
        int m = (c0 - 7 + j) & (M - 1);
        ev[j] = buf[SW(2 * m)];
        od[j] = buf[SW(2 * m + 1)];
    }
    if constexpr (WAVE) wave_sync(); else __syncthreads();
    #pragma unroll
    for (int j = 0; j < C; ++j) {
        float ao = 0.f, ae = 0.f;
        #pragma unroll
        for (int k = 0; k < 8; ++k) {
            ao = fmaf(wv[k], ev[j + 7 - k], ao);   // conv(even, wav)[n]
            ae = fmaf(sf[k], od[j + 7 - k], ae);   // conv(odd, scaling)[n]
        }
        int n = c0 + j;
        buf[SW(n)] = od[j + 7] - ao;               // odd_u -> next approx
        float d = hthr(ev[j + 7] - ae, a, bp, bm); // threshold(even_u)
        loss += fabsf(d);
        buf[SW(M + n)] = d;                        // det_l nests at [M:2M)
    }
    if constexpr (WAVE) wave_sync(); else __syncthreads();
}

// Inverse lifting level, fully in LDS: approx buf[0:M) + det buf[M:2M)
// -> buf[0:2M) interleaved [even_rest, odd_rest]. Register-staged.
template<int C, bool WAVE>
__device__ __forceinline__ void rec_level(float* __restrict__ buf, int M, int tid,
                                          const float* sf, const float* ws)
{
    const int c0 = tid * C;
    float od[C + 7], dt[C + 7];
    #pragma unroll
    for (int j = 0; j < C + 7; ++j) {
        int m = (c0 + j) & (M - 1);
        od[j] = buf[SW(m)];
        dt[j] = buf[SW(M + m)];
    }
    if constexpr (WAVE) wave_sync(); else __syncthreads();
    #pragma unroll
    for (int j = 0; j < C; ++j) {
        float ae = 0.f, ao = 0.f;
        #pragma unroll
        for (int k = 0; k < 8; ++k) {
            ae = fmaf(sf[k], od[j + k], ae);   // corr(odd, scaling)[n]
            ao = fmaf(ws[k], dt[j + k], ao);   // corr(even, ws)[n]
        }
        int n = c0 + j;
        buf[SW(2 * n)]     = dt[j] + ae;       // even_rest
        buf[SW(2 * n + 1)] = od[j] + ao;       // odd_rest
    }
    if constexpr (WAVE) wave_sync(); else __syncthreads();
}

// det0 lives in global scratch with a TRANSPOSED block layout so that both the
// forward stores and inverse loads are lane-coalesced float4:
//   det0[32*t + j]  ->  dtr[(j>>2)*4096 + 4*t + (j&3)]
// USE_WS=true: dtr = d_ws (disjoint from out -> no WAR at inverse level 0).
// USE_WS=false: dtr = out[0:32768) (fallback; needs full pre-stage + barrier).
template<bool USE_WS>
__global__ __launch_bounds__(TPB)
__attribute__((amdgpu_waves_per_eu(4, 4)))
void wavelet_vcycle_kernel(
    const float* __restrict__ x, const float* __restrict__ scaling,
    const float* __restrict__ scaling_rec, const float* __restrict__ pa,
    const float* __restrict__ pbp, const float* __restrict__ pbm,
    float* __restrict__ out, float* __restrict__ wsp)
{
    extern __shared__ float buf[];                 // 32768 floats = 128 KiB
    __shared__ float lossbuf[16];
    const int tid  = threadIdx.x;
    const int lane = tid & 63;
    const int wv_id = tid >> 6;
    const int row = blockIdx.x;
    const float* xr = x + (size_t)row * ROWLEN;
    float* outr = out + (size_t)row * ROWLEN;
    float* dtr = USE_WS ? (wsp + (size_t)row * 32768) : outr;
    const float a = rfl(pa[0]), bp = rfl(pbp[0]), bm = rfl(pbm[0]);
    float loss = 0.f;
    float sf[8], wv8[8];

    // ---------- forward level 0: x (global, reg-staged float4) -> approx_1 (LDS)
    //            det_0 -> dtr (transposed float4). Two passes of C=16. ----------
    ldf_fwd(scaling, scaling_rec, 0, sf, wv8);
    #pragma unroll
    for (int p = 0; p < 2; ++p) {
        const int c0 = tid * 32 + p * 16;
        float ev[24], od[24];
        #pragma unroll
        for (int i = 0; i < 12; ++i) {
            int mm = (c0 - 8 + 2 * i) & 32767;     // mm even -> no intra-vec wrap
            float4 v = *(const float4*)(xr + 2 * mm);
            ev[2 * i]     = v.x;  od[2 * i]     = v.y;
            ev[2 * i + 1] = v.z;  od[2 * i + 1] = v.w;
        }
        float dq[4];
        #pragma unroll
        for (int j = 0; j < 16; ++j) {
            float ao = 0.f, ae = 0.f;
            #pragma unroll
            for (int k = 0; k < 8; ++k) {
                ao = fmaf(wv8[k], ev[j + 8 - k], ao);
                ae = fmaf(sf[k],  od[j + 8 - k], ae);
            }
            buf[SW(c0 + j)] = od[j + 8] - ao;                // approx_1
            float d = hthr(ev[j + 8] - ae, a, bp, bm);
            loss += fabsf(d);
            dq[j & 3] = d;
            if ((j & 3) == 3) {
                *(float4*)(dtr + ((p * 4 + (j >> 2)) * 4096 + 4 * tid)) =
                    make_float4(dq[0], dq[1], dq[2], dq[3]);
            }
        }
    }
    __syncthreads();

    // ---------- forward levels 1..4 (all threads; det_l -> LDS [M:2M)) ----------
    ldf_fwd(scaling, scaling_rec, 1, sf, wv8); fwd_level<16, false>(buf, 16384, tid, sf, wv8, a, bp, bm, loss);
    ldf_fwd(scaling, scaling_rec, 2, sf, wv8); fwd_level< 8, false>(buf,  8192, tid, sf, wv8, a, bp, bm, loss);
    ldf_fwd(scaling, scaling_rec, 3, sf, wv8); fwd_level< 4, false>(buf,  4096, tid, sf, wv8, a, bp, bm, loss);
    ldf_fwd(scaling, scaling_rec, 4, sf, wv8); fwd_level< 2, false>(buf,  2048, tid, sf, wv8, a, bp, bm, loss);

    // ---------- deep levels 5..9 + final threshold + inverse 9..5:
    //            single wave, no block barriers ----------
    if (wv_id == 0) {
        ldf_fwd(scaling, scaling_rec, 5, sf, wv8); fwd_level<16, true>(buf, 1024, lane, sf, wv8, a, bp, bm, loss);
        ldf_fwd(scaling, scaling_rec, 6, sf, wv8); fwd_level< 8, true>(buf,  512, lane, sf, wv8, a, bp, bm, loss);
        ldf_fwd(scaling, scaling_rec, 7, sf, wv8); fwd_level< 4, true>(buf,  256, lane, sf, wv8, a, bp, bm, loss);
        ldf_fwd(scaling, scaling_rec, 8, sf, wv8); fwd_level< 2, true>(buf,  128, lane, sf, wv8, a, bp, bm, loss);
        ldf_fwd(scaling, scaling_rec, 9, sf, wv8); fwd_level< 1, true>(buf,   64, lane, sf, wv8, a, bp, bm, loss);

        // threshold approx_10 (filtered[-1]); same-lane read/write, no sync
        float v = buf[SW(lane)];
        float f = hthr(v, a, bp, bm);
        loss += fabsf(f);
        buf[SW(lane)] = f;
        wave_sync();                               // cross-lane RAW for rec stage

        ldf_rec(scaling, scaling_rec, 9, sf, wv8); rec_level< 1, true>(buf,   64, lane, sf, wv8);
        ldf_rec(scaling, scaling_rec, 8, sf, wv8); rec_level< 2, true>(buf,  128, lane, sf, wv8);
        ldf_rec(scaling, scaling_rec, 7, sf, wv8); rec_level< 4, true>(buf,  256, lane, sf, wv8);
        ldf_rec(scaling, scaling_rec, 6, sf, wv8); rec_level< 8, true>(buf,  512, lane, sf, wv8);
        ldf_rec(scaling, scaling_rec, 5, sf, wv8); rec_level<16, true>(buf, 1024, lane, sf, wv8);
    }

    // ---------- reg_loss reduction (its barrier doubles as the post-deep sync) ----------
    {
        float l = loss;
        #pragma unroll
        for (int off = 32; off > 0; off >>= 1) l += __shfl_down(l, off, 64);
        if (lane == 0) lossbuf[wv_id] = l;
    }
    __syncthreads();
    if (tid == 0) {
        float s = 0.f;
        #pragma unroll
        for (int w = 0; w < 16; ++w) s += lossbuf[w];
        atomicAdd(out + LOSS_IDX, s);
    }

    // ---------- inverse levels 4..1 (all threads) ----------
    ldf_rec(scaling, scaling_rec, 4, sf, wv8); rec_level< 2, false>(buf,  2048, tid, sf, wv8);
    ldf_rec(scaling, scaling_rec, 3, sf, wv8); rec_level< 4, false>(buf,  4096, tid, sf, wv8);
    ldf_rec(scaling, scaling_rec, 2, sf, wv8); rec_level< 8, false>(buf,  8192, tid, sf, wv8);
    ldf_rec(scaling, scaling_rec, 1, sf, wv8); rec_level<16, false>(buf, 16384, tid, sf, wv8);

    // ---------- inverse level 0: approx_1 (LDS) + det_0 (dtr, float4)
    //            -> out (global float4). ----------
    ldf_rec(scaling, scaling_rec, 0, sf, wv8);
    const int t1 = (tid + 1) & 1023;               // circular neighbor (same row)
    if constexpr (USE_WS) {
        // dtr disjoint from out -> per-pass staging, no barrier.
        #pragma unroll
        for (int p = 0; p < 2; ++p) {
            const int c0 = tid * 32 + p * 16;
            float od[23], dt[24];
            #pragma unroll
            for (int j = 0; j < 23; ++j) od[j] = buf[SW((c0 + j) & 32767)];
            if (p == 0) {
                #pragma unroll
                for (int b = 0; b < 6; ++b) {
                    float4 v = *(const float4*)(dtr + (b * 4096 + 4 * tid));
                    dt[4*b] = v.x; dt[4*b+1] = v.y; dt[4*b+2] = v.z; dt[4*b+3] = v.w;
                }
            } else {
                #pragma unroll
                for (int b = 4; b < 8; ++b) {
                    float4 v = *(const float4*)(dtr + (b * 4096 + 4 * tid));
                    dt[4*(b-4)] = v.x; dt[4*(b-4)+1] = v.y; dt[4*(b-4)+2] = v.z; dt[4*(b-4)+3] = v.w;
                }
                float4 v0 = *(const float4*)(dtr + (0 * 4096 + 4 * t1));
                dt[16] = v0.x; dt[17] = v0.y; dt[18] = v0.z; dt[19] = v0.w;
                float4 v1 = *(const float4*)(dtr + (1 * 4096 + 4 * t1));
                dt[20] = v1.x; dt[21] = v1.y; dt[22] = v1.z; dt[23] = v1.w;
            }
            #pragma unroll
            for (int i = 0; i < 8; ++i) {
                float e2[2], o2[2];
                #pragma unroll
                for (int q = 0; q < 2; ++q) {
                    const int j = 2 * i + q;
                    float ae = 0.f, ao = 0.f;
                    #pragma unroll
                    for (int k = 0; k < 8; ++k) {
                        ae = fmaf(sf[k],  od[j + k], ae);
                        ao = fmaf(wv8[k], dt[j + k], ao);
                    }
                    e2[q] = dt[j] + ae;            // even_rest
                    o2[q] = od[j] + ao;            // odd_rest
                }
                *(float4*)(outr + 2 * (c0 + 2 * i)) = make_float4(e2[0], o2[0], e2[1], o2[1]);
            }
        }
    } else {
        // dtr aliases out[0:32768): pre-stage ALL det0 reads, barrier, then write.
        float dtA[40];
        #pragma unroll
        for (int b = 0; b < 8; ++b) {
            float4 v = *(const float4*)(dtr + (b * 4096 + 4 * tid));
            dtA[4*b] = v.x; dtA[4*b+1] = v.y; dtA[4*b+2] = v.z; dtA[4*b+3] = v.w;
        }
        {
            float4 v0 = *(const float4*)(dtr + (0 * 4096 + 4 * t1));
            dtA[32] = v0.x; dtA[33] = v0.y; dtA[34] = v0.z; dtA[35] = v0.w;
            float4 v1 = *(const float4*)(dtr + (1 * 4096 + 4 * t1));
            dtA[36] = v1.x; dtA[37] = v1.y; dtA[38] = v1.z; dtA[39] = v1.w;
        }
        __syncthreads();               // all det0 reads complete before any write
        #pragma unroll
        for (int p = 0; p < 2; ++p) {
            const int c0 = tid * 32 + p * 16;
            float od[23];
            #pragma unroll
            for (int j = 0; j < 23; ++j) od[j] = buf[SW((c0 + j) & 32767)];
            #pragma unroll
            for (int i = 0; i < 8; ++i) {
                float e2[2], o2[2];
                #pragma unroll
                for (int q = 0; q < 2; ++q) {
                    const int j = 2 * i + q;
                    float ae = 0.f, ao = 0.f;
                    #pragma unroll
                    for (int k = 0; k < 8; ++k) {
                        ae = fmaf(sf[k],  od[j + k], ae);
                        ao = fmaf(wv8[k], dtA[p * 16 + j + k], ao);
                    }
                    e2[q] = dtA[p * 16 + j] + ae;
                    o2[q] = od[j] + ao;
                }
                *(float4*)(outr + 2 * (c0 + 2 * i)) = make_float4(e2[0], o2[0], e2[1], o2[1]);
            }
        }
    }
}

extern "C" void kernel_launch(void* const* d_in, const int* in_sizes, int n_in,
                              void* d_out, int out_size, void* d_ws, size_t ws_size,
                              hipStream_t stream) {
    const float* x           = (const float*)d_in[0];
    const float* scaling     = (const float*)d_in[1];
    const float* scaling_rec = (const float*)d_in[2];
    const float* p_alpha     = (const float*)d_in[3];
    const float* p_bp        = (const float*)d_in[4];
    const float* p_bm        = (const float*)d_in[5];
    float* out = (float*)d_out;

    // zero the loss accumulator each launch (graph-capture safe)
    hipMemsetAsync(out + LOSS_IDX, 0, sizeof(float), stream);

    const size_t det0_bytes = (size_t)NROWS * 32768 * sizeof(float);
    if (ws_size >= det0_bytes) {
        wavelet_vcycle_kernel<true><<<dim3(NROWS), dim3(TPB), 32768 * sizeof(float), stream>>>(
            x, scaling, scaling_rec, p_alpha, p_bp, p_bm, out, (float*)d_ws);
    } else {
        wavelet_vcycle_kernel<false><<<dim3(NROWS), dim3(TPB), 32768 * sizeof(float), stream>>>(
            x, scaling, scaling_rec, p_alpha, p_bp, p_bm, out, (float*)d_ws);
    }
}

// Round 6
// 93.223 us; speedup vs baseline: 1.0729x; 1.0729x over previous
//
#include <hip/hip_runtime.h>

#define NROWS 256
#define ROWLEN 65536
#define TPB 1024
#define LOSS_IDX ((size_t)NROWS * (size_t)ROWLEN)

// Two-level XOR swizzle: bijective (only bits 0-4 modified, key bits >=5
// unchanged). With per-thread chunk ownership, all large-level strided
// accesses become conflict-free; deep-level strides (>=512 floats) spread too.
__device__ __forceinline__ int SW(int i) {
    return i ^ (((i >> 5) ^ (i >> 10)) & 31);
}

// Force a wave-uniform float into an SGPR (filter taps).
__device__ __forceinline__ float rfl(float x) {
    union { float f; int i; } u; u.f = x;
    u.i = __builtin_amdgcn_readfirstlane(u.i);
    return u.f;
}

__device__ __forceinline__ float sigm(float z) { return 1.0f / (1.0f + __expf(-z)); }

__device__ __forceinline__ float hthr(float v, float a, float bp, float bm) {
    return v * (sigm(a * (v - bp)) + sigm(-a * (v + bm)));
}

// Intra-wave "barrier": valid only when producer and consumer lanes are in the
// SAME wave (deep levels run entirely in wave 0).
__device__ __forceinline__ void wave_sync() {
    __builtin_amdgcn_wave_barrier();
    __threadfence_block();
    __builtin_amdgcn_wave_barrier();
}

__device__ __forceinline__ void ldf_fwd(const float* sc, const float* rec, int lvl,
                                        float* sf, float* wv) {
    #pragma unroll
    for (int i = 0; i < 8; ++i) sf[i] = rfl(sc[lvl * 8 + i]);
    #pragma unroll
    for (int i = 0; i < 8; ++i) {
        float r = rfl(rec[lvl * 8 + 7 - i]);
        wv[i] = (i & 1) ? -r : r;            // _compute_wavelet
    }
}

__device__ __forceinline__ void ldf_rec(const float* sc, const float* rec, int lvl,
                                        float* sf, float* ws) {
    #pragma unroll
    for (int i = 0; i < 8; ++i) sf[i] = rfl(sc[lvl * 8 + i]);
    #pragma unroll
    for (int i = 0; i < 8; ++i) {
        float r = rfl(rec[lvl * 8 + 7 - i]);
        ws[i] = (i & 1) ? r : -r;            // _compute_wavelet_synthesis
    }
}

// ---------- strided in-place forward lifting level ----------
// approx elements at stride S (pair n: even @ 2nS, odd @ (2n+1)S).
// Writes approx_{l+1}[n] -> 2nS, thresholded det_l[n] -> (2n+1)S (in place).
// Cross-thread WAR limited to the 7-pair left halo (staged in regs).
// Rolling 8-register window; ~40 VGPRs live -> no spills.
template<int C, int S, int M, bool WAVE>
__device__ __forceinline__ void fwd_level(float* __restrict__ buf, int tid,
                                          const float* sf, const float* wv,
                                          float a, float bp, float bm, float& loss)
{
    const int c0 = tid * C;
    float ev[8], od[8];
    #pragma unroll
    for (int k = 0; k < 7; ++k) {                // left halo: pairs c0-7..c0-1
        int m = (c0 - 7 + k) & (M - 1);
        ev[k] = buf[SW(2 * m * S)];
        od[k] = buf[SW((2 * m + 1) * S)];
    }
    if constexpr (WAVE) wave_sync(); else __syncthreads();
    float ne = buf[SW(2 * c0 * S)];              // 1-ahead prefetch
    float no = buf[SW((2 * c0 + 1) * S)];
    #pragma unroll
    for (int j = 0; j < C; ++j) {
        const int n = c0 + j;
        ev[7] = ne; od[7] = no;
        if (j + 1 < C) {
            ne = buf[SW(2 * (n + 1) * S)];
            no = buf[SW((2 * (n + 1) + 1) * S)];
        }
        float ao = 0.f, ae = 0.f;
        #pragma unroll
        for (int k = 0; k < 8; ++k) {
            ao = fmaf(wv[k], ev[7 - k], ao);     // conv(even, wav)[n]
            ae = fmaf(sf[k], od[7 - k], ae);     // conv(odd, scaling)[n]
        }
        buf[SW(2 * n * S)] = od[7] - ao;         // next approx (even slot)
        float d = hthr(ev[7] - ae, a, bp, bm);   // thresholded detail
        loss += fabsf(d);
        buf[SW((2 * n + 1) * S)] = d;            // det stays in odd slot
        #pragma unroll
        for (int k = 0; k < 7; ++k) { ev[k] = ev[k + 1]; od[k] = od[k + 1]; }
    }
    if constexpr (WAVE) wave_sync(); else __syncthreads();
}

// ---------- strided in-place inverse lifting level ----------
// Reads approx_{l+1}[n] @ 2nS and det_l[n] @ (2n+1)S, writes even_rest -> 2nS,
// odd_rest -> (2n+1)S. Right halo (7 pairs) staged in regs.
template<int C, int S, int M, bool WAVE>
__device__ __forceinline__ void rec_level(float* __restrict__ buf, int tid,
                                          const float* sf, const float* ws)
{
    const int c0 = tid * C;
    float ha[7], hd[7];
    #pragma unroll
    for (int k = 0; k < 7; ++k) {                // right halo: pairs c0+C..c0+C+6
        int m = (c0 + C + k) & (M - 1);
        ha[k] = buf[SW(2 * m * S)];
        hd[k] = buf[SW((2 * m + 1) * S)];
    }
    if constexpr (WAVE) wave_sync(); else __syncthreads();
    float ap[8], dt[8];
    #pragma unroll
    for (int k = 0; k < 8; ++k) {                // window [c0 .. c0+7]
        if (k < C) {
            ap[k] = buf[SW(2 * (c0 + k) * S)];
            dt[k] = buf[SW((2 * (c0 + k) + 1) * S)];
        } else {
            ap[k] = ha[k - C];
            dt[k] = hd[k - C];
        }
    }
    #pragma unroll
    for (int j = 0; j < C; ++j) {
        const int n = c0 + j;
        float er = 0.f, orr = 0.f;
        #pragma unroll
        for (int k = 0; k < 8; ++k) {
            er  = fmaf(sf[k], ap[k], er);        // corr(approx, scaling)[n]
            orr = fmaf(ws[k], dt[k], orr);       // corr(det, ws)[n]
        }
        er  += dt[0];                            // even_rest[n]
        orr += ap[0];                            // odd_rest[n]
        buf[SW(2 * n * S)] = er;
        buf[SW((2 * n + 1) * S)] = orr;
        if (j + 1 < C) {
            #pragma unroll
            for (int k = 0; k < 7; ++k) { ap[k] = ap[k + 1]; dt[k] = dt[k + 1]; }
            const int nn = n + 8;
            if (j + 8 < C) {
                ap[7] = buf[SW(2 * nn * S)];
                dt[7] = buf[SW((2 * nn + 1) * S)];
            } else {
                ap[7] = ha[j + 8 - C];
                dt[7] = hd[j + 8 - C];
            }
        }
    }
    if constexpr (WAVE) wave_sync(); else __syncthreads();
}

// det0 in global scratch, transposed block layout (coalesced float4 both ways):
//   det0[32*t + j]  ->  dtr[(j>>2)*4096 + 4*t + (j&3)]
template<bool USE_WS>
__global__ __launch_bounds__(TPB)
void wavelet_vcycle_kernel(
    const float* __restrict__ x, const float* __restrict__ scaling,
    const float* __restrict__ scaling_rec, const float* __restrict__ pa,
    const float* __restrict__ pbp, const float* __restrict__ pbm,
    float* __restrict__ out, float* __restrict__ wsp)
{
    extern __shared__ float buf[];               // 32768 floats = 128 KiB
    __shared__ float lossbuf[16];
    const int tid  = threadIdx.x;
    const int lane = tid & 63;
    const int wv_id = tid >> 6;
    const int row = blockIdx.x;
    const float* xr = x + (size_t)row * ROWLEN;
    float* outr = out + (size_t)row * ROWLEN;
    float* dtr = USE_WS ? (wsp + (size_t)row * 32768) : outr;
    const float a = rfl(pa[0]), bp = rfl(pbp[0]), bm = rfl(pbm[0]);
    float loss = 0.f;
    float sf[8], wv8[8];

    // ---------- forward level 0: x (global, rolling window) -> approx_1 (LDS,
    //            stride 1), det_0 -> dtr (transposed float4). No staging arrays.
    ldf_fwd(scaling, scaling_rec, 0, sf, wv8);
    {
        const int c0 = tid * 32;                 // pair index base
        float ev[8], od[8];
        {
            const int b = 2 * c0;                // float index of pair c0
            float4 h0 = *(const float4*)(xr + ((b - 16) & 65535));
            float4 h1 = *(const float4*)(xr + ((b - 12) & 65535));
            float4 h2 = *(const float4*)(xr + ((b -  8) & 65535));
            float4 h3 = *(const float4*)(xr + ((b -  4) & 65535));
            ev[0] = h0.z; od[0] = h0.w;
            ev[1] = h1.x; od[1] = h1.y; ev[2] = h1.z; od[2] = h1.w;
            ev[3] = h2.x; od[3] = h2.y; ev[4] = h2.z; od[4] = h2.w;
            ev[5] = h3.x; od[5] = h3.y; ev[6] = h3.z; od[6] = h3.w;
        }
        float dq[4];
        #pragma unroll
        for (int jj = 0; jj < 16; ++jj) {        // one float4 = 2 pairs
            float4 v = *(const float4*)(xr + 2 * (c0 + 2 * jj));
            #pragma unroll
            for (int q = 0; q < 2; ++q) {
                const int j = 2 * jj + q;
                const int n = c0 + j;
                ev[7] = (q == 0) ? v.x : v.z;
                od[7] = (q == 0) ? v.y : v.w;
                float ao = 0.f, ae = 0.f;
                #pragma unroll
                for (int k = 0; k < 8; ++k) {
                    ao = fmaf(wv8[k], ev[7 - k], ao);
                    ae = fmaf(sf[k],  od[7 - k], ae);
                }
                buf[SW(n)] = od[7] - ao;         // approx_1[n]
                float d = hthr(ev[7] - ae, a, bp, bm);
                loss += fabsf(d);
                dq[j & 3] = d;
                if ((j & 3) == 3)
                    *(float4*)(dtr + ((j >> 2) * 4096 + 4 * tid)) =
                        make_float4(dq[0], dq[1], dq[2], dq[3]);
                #pragma unroll
                for (int k = 0; k < 7; ++k) { ev[k] = ev[k + 1]; od[k] = od[k + 1]; }
            }
        }
    }
    __syncthreads();

    // ---------- forward levels 1..4 (full block; strided in-place) ----------
    ldf_fwd(scaling, scaling_rec, 1, sf, wv8); fwd_level<16, 1, 16384, false>(buf, tid, sf, wv8, a, bp, bm, loss);
    ldf_fwd(scaling, scaling_rec, 2, sf, wv8); fwd_level< 8, 2,  8192, false>(buf, tid, sf, wv8, a, bp, bm, loss);
    ldf_fwd(scaling, scaling_rec, 3, sf, wv8); fwd_level< 4, 4,  4096, false>(buf, tid, sf, wv8, a, bp, bm, loss);
    ldf_fwd(scaling, scaling_rec, 4, sf, wv8); fwd_level< 2, 8,  2048, false>(buf, tid, sf, wv8, a, bp, bm, loss);

    // ---------- deep levels 5..9 + threshold + inverse 9..5: single wave ----------
    if (wv_id == 0) {
        ldf_fwd(scaling, scaling_rec, 5, sf, wv8); fwd_level<16,  16, 1024, true>(buf, lane, sf, wv8, a, bp, bm, loss);
        ldf_fwd(scaling, scaling_rec, 6, sf, wv8); fwd_level< 8,  32,  512, true>(buf, lane, sf, wv8, a, bp, bm, loss);
        ldf_fwd(scaling, scaling_rec, 7, sf, wv8); fwd_level< 4,  64,  256, true>(buf, lane, sf, wv8, a, bp, bm, loss);
        ldf_fwd(scaling, scaling_rec, 8, sf, wv8); fwd_level< 2, 128,  128, true>(buf, lane, sf, wv8, a, bp, bm, loss);
        ldf_fwd(scaling, scaling_rec, 9, sf, wv8); fwd_level< 1, 256,   64, true>(buf, lane, sf, wv8, a, bp, bm, loss);

        // threshold approx_10: 64 elements at stride 512 (same-lane r/w)
        float v = buf[SW(lane * 512)];
        float f = hthr(v, a, bp, bm);
        loss += fabsf(f);
        buf[SW(lane * 512)] = f;
        wave_sync();

        ldf_rec(scaling, scaling_rec, 9, sf, wv8); rec_level< 1, 256,   64, true>(buf, lane, sf, wv8);
        ldf_rec(scaling, scaling_rec, 8, sf, wv8); rec_level< 2, 128,  128, true>(buf, lane, sf, wv8);
        ldf_rec(scaling, scaling_rec, 7, sf, wv8); rec_level< 4,  64,  256, true>(buf, lane, sf, wv8);
        ldf_rec(scaling, scaling_rec, 6, sf, wv8); rec_level< 8,  32,  512, true>(buf, lane, sf, wv8);
        ldf_rec(scaling, scaling_rec, 5, sf, wv8); rec_level<16,  16, 1024, true>(buf, lane, sf, wv8);
    }

    // ---------- reg_loss reduction (its barrier doubles as the post-deep sync) ----------
    {
        float l = loss;
        #pragma unroll
        for (int off = 32; off > 0; off >>= 1) l += __shfl_down(l, off, 64);
        if (lane == 0) lossbuf[wv_id] = l;
    }
    __syncthreads();
    if (tid == 0) {
        float s = 0.f;
        #pragma unroll
        for (int w = 0; w < 16; ++w) s += lossbuf[w];
        atomicAdd(out + LOSS_IDX, s);
    }

    // ---------- inverse levels 4..1 (full block) ----------
    ldf_rec(scaling, scaling_rec, 4, sf, wv8); rec_level< 2, 8, 2048, false>(buf, tid, sf, wv8);
    ldf_rec(scaling, scaling_rec, 3, sf, wv8); rec_level< 4, 4, 4096, false>(buf, tid, sf, wv8);
    ldf_rec(scaling, scaling_rec, 2, sf, wv8); rec_level< 8, 2, 8192, false>(buf, tid, sf, wv8);
    ldf_rec(scaling, scaling_rec, 1, sf, wv8); rec_level<16, 1, 16384, false>(buf, tid, sf, wv8);

    // ---------- inverse level 0: approx_1 (LDS, read-only -> no barrier) +
    //            det_0 (dtr, float4) -> out (global float4). ----------
    ldf_rec(scaling, scaling_rec, 0, sf, wv8);
    const int t1 = (tid + 1) & 1023;
    if constexpr (USE_WS) {
        #pragma unroll
        for (int p = 0; p < 2; ++p) {
            const int c0 = tid * 32 + p * 16;    // pair index
            float dA[24];                        // det[c0 .. c0+23]
            if (p == 0) {
                #pragma unroll
                for (int b = 0; b < 6; ++b) {
                    float4 v = *(const float4*)(dtr + (b * 4096 + 4 * tid));
                    dA[4*b]=v.x; dA[4*b+1]=v.y; dA[4*b+2]=v.z; dA[4*b+3]=v.w;
                }
            } else {
                #pragma unroll
                for (int b = 4; b < 8; ++b) {
                    float4 v = *(const float4*)(dtr + (b * 4096 + 4 * tid));
                    dA[4*(b-4)]=v.x; dA[4*(b-4)+1]=v.y; dA[4*(b-4)+2]=v.z; dA[4*(b-4)+3]=v.w;
                }
                float4 v0 = *(const float4*)(dtr + (0 * 4096 + 4 * t1));
                dA[16]=v0.x; dA[17]=v0.y; dA[18]=v0.z; dA[19]=v0.w;
                float4 v1 = *(const float4*)(dtr + (1 * 4096 + 4 * t1));
                dA[20]=v1.x; dA[21]=v1.y; dA[22]=v1.z; dA[23]=v1.w;
            }
            float ap[8];
            #pragma unroll
            for (int k = 0; k < 8; ++k) ap[k] = buf[SW((c0 + k) & 32767)];
            float e0 = 0.f, o0 = 0.f;
            #pragma unroll
            for (int j = 0; j < 16; ++j) {
                const int n = c0 + j;
                float er = 0.f, orr = 0.f;
                #pragma unroll
                for (int k = 0; k < 8; ++k) {
                    er  = fmaf(sf[k],  ap[k],     er);
                    orr = fmaf(wv8[k], dA[j + k], orr);
                }
                er  += dA[j];
                orr += ap[0];
                if ((j & 1) == 0) { e0 = er; o0 = orr; }
                else *(float4*)(outr + 2 * (n - 1)) = make_float4(e0, o0, er, orr);
                if (j < 15) {
                    #pragma unroll
                    for (int k = 0; k < 7; ++k) ap[k] = ap[k + 1];
                    ap[7] = buf[SW((n + 8) & 32767)];
                }
            }
        }
    } else {
        // dtr aliases out[0:32768): stage ALL det0 reads, barrier, then write.
        float dAll[40];
        #pragma unroll
        for (int b = 0; b < 8; ++b) {
            float4 v = *(const float4*)(dtr + (b * 4096 + 4 * tid));
            dAll[4*b]=v.x; dAll[4*b+1]=v.y; dAll[4*b+2]=v.z; dAll[4*b+3]=v.w;
        }
        {
            float4 v0 = *(const float4*)(dtr + (0 * 4096 + 4 * t1));
            dAll[32]=v0.x; dAll[33]=v0.y; dAll[34]=v0.z; dAll[35]=v0.w;
            float4 v1 = *(const float4*)(dtr + (1 * 4096 + 4 * t1));
            dAll[36]=v1.x; dAll[37]=v1.y; dAll[38]=v1.z; dAll[39]=v1.w;
        }
        __syncthreads();
        #pragma unroll
        for (int p = 0; p < 2; ++p) {
            const int c0 = tid * 32 + p * 16;
            float ap[8];
            #pragma unroll
            for (int k = 0; k < 8; ++k) ap[k] = buf[SW((c0 + k) & 32767)];
            float e0 = 0.f, o0 = 0.f;
            #pragma unroll
            for (int j = 0; j < 16; ++j) {
                const int n = c0 + j;
                float er = 0.f, orr = 0.f;
                #pragma unroll
                for (int k = 0; k < 8; ++k) {
                    er  = fmaf(sf[k],  ap[k],              er);
                    orr = fmaf(wv8[k], dAll[p * 16 + j + k], orr);
                }
                er  += dAll[p * 16 + j];
                orr += ap[0];
                if ((j & 1) == 0) { e0 = er; o0 = orr; }
                else *(float4*)(outr + 2 * (n - 1)) = make_float4(e0, o0, er, orr);
                if (j < 15) {
                    #pragma unroll
                    for (int k = 0; k < 7; ++k) ap[k] = ap[k + 1];
                    ap[7] = buf[SW((n + 8) & 32767)];
                }
            }
        }
    }
}

extern "C" void kernel_launch(void* const* d_in, const int* in_sizes, int n_in,
                              void* d_out, int out_size, void* d_ws, size_t ws_size,
                              hipStream_t stream) {
    const float* x           = (const float*)d_in[0];
    const float* scaling     = (const float*)d_in[1];
    const float* scaling_rec = (const float*)d_in[2];
    const float* p_alpha     = (const float*)d_in[3];
    const float* p_bp        = (const float*)d_in[4];
    const float* p_bm        = (const float*)d_in[5];
    float* out = (float*)d_out;

    // zero the loss accumulator each launch (graph-capture safe)
    hipMemsetAsync(out + LOSS_IDX, 0, sizeof(float), stream);

    const size_t det0_bytes = (size_t)NROWS * 32768 * sizeof(float);
    if (ws_size >= det0_bytes) {
        wavelet_vcycle_kernel<true><<<dim3(NROWS), dim3(TPB), 32768 * sizeof(float), stream>>>(
            x, scaling, scaling_rec, p_alpha, p_bp, p_bm, out, (float*)d_ws);
    } else {
        wavelet_vcycle_kernel<false><<<dim3(NROWS), dim3(TPB), 32768 * sizeof(float), stream>>>(
            x, scaling, scaling_rec, p_alpha, p_bp, p_bm, out, (float*)d_ws);
    }
}

// Round 7
// 85.542 us; speedup vs baseline: 1.1692x; 1.0898x over previous
//
#include <hip/hip_runtime.h>

#define NROWS 256
#define ROWLEN 65536
#define TPB 1024
#define LOSS_IDX ((size_t)NROWS * (size_t)ROWLEN)

// Two-level XOR swizzle: bijective (only bits 0-4 modified). Spreads strided
// accesses across banks. Applied to EVERY access of buf[].
__device__ __forceinline__ int SW(int i) {
    return i ^ (((i >> 5) ^ (i >> 10)) & 31);
}

// Force a wave-uniform float into an SGPR (filter taps).
__device__ __forceinline__ float rfl(float x) {
    union { float f; int i; } u; u.f = x;
    u.i = __builtin_amdgcn_readfirstlane(u.i);
    return u.f;
}

__device__ __forceinline__ float sigm(float z) { return 1.0f / (1.0f + __expf(-z)); }

__device__ __forceinline__ float hthr(float v, float a, float bp, float bm) {
    return v * (sigm(a * (v - bp)) + sigm(-a * (v + bm)));
}

// Intra-wave "barrier": valid only when producer and consumer lanes are in the
// SAME wave (deep levels run entirely in wave 0).
__device__ __forceinline__ void wave_sync() {
    __builtin_amdgcn_wave_barrier();
    __threadfence_block();
    __builtin_amdgcn_wave_barrier();
}

__device__ __forceinline__ void ldf_fwd(const float* sc, const float* rec, int lvl,
                                        float* sf, float* wv) {
    #pragma unroll
    for (int i = 0; i < 8; ++i) sf[i] = rfl(sc[lvl * 8 + i]);
    #pragma unroll
    for (int i = 0; i < 8; ++i) {
        float r = rfl(rec[lvl * 8 + 7 - i]);
        wv[i] = (i & 1) ? -r : r;            // _compute_wavelet
    }
}

__device__ __forceinline__ void ldf_rec(const float* sc, const float* rec, int lvl,
                                        float* sf, float* ws) {
    #pragma unroll
    for (int i = 0; i < 8; ++i) sf[i] = rfl(sc[lvl * 8 + i]);
    #pragma unroll
    for (int i = 0; i < 8; ++i) {
        float r = rfl(rec[lvl * 8 + 7 - i]);
        ws[i] = (i & 1) ? r : -r;            // _compute_wavelet_synthesis
    }
}

// ---------- strided in-place forward lifting level ----------
// approx elements at stride S (pair n: even @ 2nS, odd @ (2n+1)S).
// Writes approx_{l+1}[n] -> 2nS, thresholded det_l[n] -> (2n+1)S (in place).
// Cross-thread WAR limited to the 7-pair left halo (staged in regs).
template<int C, int S, int M, bool WAVE>
__device__ __forceinline__ void fwd_level(float* __restrict__ buf, int tid,
                                          const float* sf, const float* wv,
                                          float a, float bp, float bm, float& loss)
{
    const int c0 = tid * C;
    float ev[8], od[8];
    #pragma unroll
    for (int k = 0; k < 7; ++k) {                // left halo: pairs c0-7..c0-1
        int m = (c0 - 7 + k) & (M - 1);
        ev[k] = buf[SW(2 * m * S)];
        od[k] = buf[SW((2 * m + 1) * S)];
    }
    if constexpr (WAVE) wave_sync(); else __syncthreads();
    float ne = buf[SW(2 * c0 * S)];              // 1-ahead prefetch
    float no = buf[SW((2 * c0 + 1) * S)];
    #pragma unroll
    for (int j = 0; j < C; ++j) {
        const int n = c0 + j;
        ev[7] = ne; od[7] = no;
        if (j + 1 < C) {
            ne = buf[SW(2 * (n + 1) * S)];
            no = buf[SW((2 * (n + 1) + 1) * S)];
        }
        float ao = 0.f, ae = 0.f;
        #pragma unroll
        for (int k = 0; k < 8; ++k) {
            ao = fmaf(wv[k], ev[7 - k], ao);     // conv(even, wav)[n]
            ae = fmaf(sf[k], od[7 - k], ae);     // conv(odd, scaling)[n]
        }
        buf[SW(2 * n * S)] = od[7] - ao;         // next approx (even slot)
        float d = hthr(ev[7] - ae, a, bp, bm);   // thresholded detail
        loss += fabsf(d);
        buf[SW((2 * n + 1) * S)] = d;            // det stays in odd slot
        #pragma unroll
        for (int k = 0; k < 7; ++k) { ev[k] = ev[k + 1]; od[k] = od[k + 1]; }
    }
    if constexpr (WAVE) wave_sync(); else __syncthreads();
}

// ---------- strided in-place inverse lifting level ----------
template<int C, int S, int M, bool WAVE>
__device__ __forceinline__ void rec_level(float* __restrict__ buf, int tid,
                                          const float* sf, const float* ws)
{
    const int c0 = tid * C;
    float ha[7], hd[7];
    #pragma unroll
    for (int k = 0; k < 7; ++k) {                // right halo: pairs c0+C..c0+C+6
        int m = (c0 + C + k) & (M - 1);
        ha[k] = buf[SW(2 * m * S)];
        hd[k] = buf[SW((2 * m + 1) * S)];
    }
    if constexpr (WAVE) wave_sync(); else __syncthreads();
    float ap[8], dt[8];
    #pragma unroll
    for (int k = 0; k < 8; ++k) {                // window [c0 .. c0+7]
        if (k < C) {
            ap[k] = buf[SW(2 * (c0 + k) * S)];
            dt[k] = buf[SW((2 * (c0 + k) + 1) * S)];
        } else {
            ap[k] = ha[k - C];
            dt[k] = hd[k - C];
        }
    }
    #pragma unroll
    for (int j = 0; j < C; ++j) {
        const int n = c0 + j;
        float er = 0.f, orr = 0.f;
        #pragma unroll
        for (int k = 0; k < 8; ++k) {
            er  = fmaf(sf[k], ap[k], er);        // corr(approx, scaling)[n]
            orr = fmaf(ws[k], dt[k], orr);       // corr(det, ws)[n]
        }
        er  += dt[0];                            // even_rest[n]
        orr += ap[0];                            // odd_rest[n]
        buf[SW(2 * n * S)] = er;
        buf[SW((2 * n + 1) * S)] = orr;
        if (j + 1 < C) {
            #pragma unroll
            for (int k = 0; k < 7; ++k) { ap[k] = ap[k + 1]; dt[k] = dt[k + 1]; }
            const int nn = n + 8;
            if (j + 8 < C) {
                ap[7] = buf[SW(2 * nn * S)];
                dt[7] = buf[SW((2 * nn + 1) * S)];
            } else {
                ap[7] = ha[j + 8 - C];
                dt[7] = hd[j + 8 - C];
            }
        }
    }
    if constexpr (WAVE) wave_sync(); else __syncthreads();
}

// amdgpu_num_vgpr(128): pin the VGPR allocation at 128 = 512/4, i.e. exactly
// the 4-waves/SIMD occupancy that the 128 KiB dynamic LDS forces anyway
// (1 block/CU, 16 waves). The default allocator targets 8 waves/SIMD
// (64 VGPRs) and spills ~45 floats/thread to scratch for occupancy that can
// never materialize; both launch_bounds and waves_per_eu failed to lift it.
__global__ __launch_bounds__(TPB)
__attribute__((amdgpu_num_vgpr(128), amdgpu_waves_per_eu(4, 4)))
void wavelet_vcycle_kernel(
    const float* __restrict__ x, const float* __restrict__ scaling,
    const float* __restrict__ scaling_rec, const float* __restrict__ pa,
    const float* __restrict__ pbp, const float* __restrict__ pbm,
    float* __restrict__ out)
{
    extern __shared__ float buf[];               // 32768 floats = 128 KiB
    __shared__ float wb[16][8];                  // wave-boundary det0 halo
    __shared__ float lossbuf[16];
    const int tid  = threadIdx.x;
    const int lane = tid & 63;
    const int wv_id = tid >> 6;
    const int row = blockIdx.x;
    const float* xr = x + (size_t)row * ROWLEN;
    float* outr = out + (size_t)row * ROWLEN;
    const float a = rfl(pa[0]), bp = rfl(pbp[0]), bm = rfl(pbm[0]);
    float loss = 0.f;
    float sf[8], wv8[8];
    float det0[32];                              // level-0 details live here

    // ---------- forward level 0: x (global, rolling window) -> approx_1 (LDS,
    //            stride 1), det_0 -> registers. ----------
    ldf_fwd(scaling, scaling_rec, 0, sf, wv8);
    {
        const int c0 = tid * 32;                 // pair index base
        float ev[8], od[8];
        {
            const int b = 2 * c0;                // float index of pair c0
            float4 h0 = *(const float4*)(xr + ((b - 16) & 65535));
            float4 h1 = *(const float4*)(xr + ((b - 12) & 65535));
            float4 h2 = *(const float4*)(xr + ((b -  8) & 65535));
            float4 h3 = *(const float4*)(xr + ((b -  4) & 65535));
            ev[0] = h0.z; od[0] = h0.w;
            ev[1] = h1.x; od[1] = h1.y; ev[2] = h1.z; od[2] = h1.w;
            ev[3] = h2.x; od[3] = h2.y; ev[4] = h2.z; od[4] = h2.w;
            ev[5] = h3.x; od[5] = h3.y; ev[6] = h3.z; od[6] = h3.w;
        }
        #pragma unroll
        for (int jj = 0; jj < 16; ++jj) {        // one float4 = 2 pairs
            float4 v = *(const float4*)(xr + 2 * (c0 + 2 * jj));
            #pragma unroll
            for (int q = 0; q < 2; ++q) {
                const int j = 2 * jj + q;
                const int n = c0 + j;
                ev[7] = (q == 0) ? v.x : v.z;
                od[7] = (q == 0) ? v.y : v.w;
                float ao = 0.f, ae = 0.f;
                #pragma unroll
                for (int k = 0; k < 8; ++k) {
                    ao = fmaf(wv8[k], ev[7 - k], ao);
                    ae = fmaf(sf[k],  od[7 - k], ae);
                }
                buf[SW(n)] = od[7] - ao;         // approx_1[n]
                float d = hthr(ev[7] - ae, a, bp, bm);
                loss += fabsf(d);
                det0[j] = d;
                #pragma unroll
                for (int k = 0; k < 7; ++k) { ev[k] = ev[k + 1]; od[k] = od[k + 1]; }
            }
        }
    }
    if (lane == 0) {                             // stash det0[0..6] for halo
        #pragma unroll
        for (int k = 0; k < 7; ++k) wb[wv_id][k] = det0[k];
    }
    __syncthreads();

    // ---------- forward levels 1..4 (full block; strided in-place) ----------
    ldf_fwd(scaling, scaling_rec, 1, sf, wv8); fwd_level<16, 1, 16384, false>(buf, tid, sf, wv8, a, bp, bm, loss);
    ldf_fwd(scaling, scaling_rec, 2, sf, wv8); fwd_level< 8, 2,  8192, false>(buf, tid, sf, wv8, a, bp, bm, loss);
    ldf_fwd(scaling, scaling_rec, 3, sf, wv8); fwd_level< 4, 4,  4096, false>(buf, tid, sf, wv8, a, bp, bm, loss);
    ldf_fwd(scaling, scaling_rec, 4, sf, wv8); fwd_level< 2, 8,  2048, false>(buf, tid, sf, wv8, a, bp, bm, loss);

    // ---------- deep levels 5..9 + threshold + inverse 9..5: single wave ----------
    if (wv_id == 0) {
        ldf_fwd(scaling, scaling_rec, 5, sf, wv8); fwd_level<16,  16, 1024, true>(buf, lane, sf, wv8, a, bp, bm, loss);
        ldf_fwd(scaling, scaling_rec, 6, sf, wv8); fwd_level< 8,  32,  512, true>(buf, lane, sf, wv8, a, bp, bm, loss);
        ldf_fwd(scaling, scaling_rec, 7, sf, wv8); fwd_level< 4,  64,  256, true>(buf, lane, sf, wv8, a, bp, bm, loss);
        ldf_fwd(scaling, scaling_rec, 8, sf, wv8); fwd_level< 2, 128,  128, true>(buf, lane, sf, wv8, a, bp, bm, loss);
        ldf_fwd(scaling, scaling_rec, 9, sf, wv8); fwd_level< 1, 256,   64, true>(buf, lane, sf, wv8, a, bp, bm, loss);

        // threshold approx_10: 64 elements at stride 512 (same-lane r/w)
        float v = buf[SW(lane * 512)];
        float f = hthr(v, a, bp, bm);
        loss += fabsf(f);
        buf[SW(lane * 512)] = f;
        wave_sync();

        ldf_rec(scaling, scaling_rec, 9, sf, wv8); rec_level< 1, 256,   64, true>(buf, lane, sf, wv8);
        ldf_rec(scaling, scaling_rec, 8, sf, wv8); rec_level< 2, 128,  128, true>(buf, lane, sf, wv8);
        ldf_rec(scaling, scaling_rec, 7, sf, wv8); rec_level< 4,  64,  256, true>(buf, lane, sf, wv8);
        ldf_rec(scaling, scaling_rec, 6, sf, wv8); rec_level< 8,  32,  512, true>(buf, lane, sf, wv8);
        ldf_rec(scaling, scaling_rec, 5, sf, wv8); rec_level<16,  16, 1024, true>(buf, lane, sf, wv8);
    }

    // ---------- reg_loss reduction (its barrier doubles as the post-deep sync) ----------
    {
        float l = loss;
        #pragma unroll
        for (int off = 32; off > 0; off >>= 1) l += __shfl_down(l, off, 64);
        if (lane == 0) lossbuf[wv_id] = l;
    }
    __syncthreads();
    if (tid == 0) {
        float s = 0.f;
        #pragma unroll
        for (int w = 0; w < 16; ++w) s += lossbuf[w];
        atomicAdd(out + LOSS_IDX, s);
    }

    // ---------- inverse levels 4..1 (full block) ----------
    ldf_rec(scaling, scaling_rec, 4, sf, wv8); rec_level< 2, 8, 2048, false>(buf, tid, sf, wv8);
    ldf_rec(scaling, scaling_rec, 3, sf, wv8); rec_level< 4, 4, 4096, false>(buf, tid, sf, wv8);
    ldf_rec(scaling, scaling_rec, 2, sf, wv8); rec_level< 8, 2, 8192, false>(buf, tid, sf, wv8);
    ldf_rec(scaling, scaling_rec, 1, sf, wv8); rec_level<16, 1, 16384, false>(buf, tid, sf, wv8);

    // ---------- inverse level 0: approx_1 (LDS, read-only -> no barrier) +
    //            det_0 (regs, shfl halo) -> out (global float4). ----------
    {
        ldf_rec(scaling, scaling_rec, 0, sf, wv8);
        float h[7];                              // neighbor thread's det0[0..6]
        #pragma unroll
        for (int k = 0; k < 7; ++k) h[k] = __shfl(det0[k], (lane + 1) & 63, 64);
        if (lane == 63) {
            #pragma unroll
            for (int k = 0; k < 7; ++k) h[k] = wb[(wv_id + 1) & 15][k];
        }
        #pragma unroll
        for (int p = 0; p < 2; ++p) {
            const int c0 = tid * 32 + p * 16;    // pair index
            float ap[8];                         // approx window [c0 .. c0+7]
            #pragma unroll
            for (int k = 0; k < 8; ++k) ap[k] = buf[SW((c0 + k) & 32767)];
            float e0 = 0.f, o0 = 0.f;
            #pragma unroll
            for (int j = 0; j < 16; ++j) {
                const int n = c0 + j;
                float er = 0.f, orr = 0.f;
                #pragma unroll
                for (int k = 0; k < 8; ++k) {
                    const int di = p * 16 + j + k;           // compile-time
                    float dv = (di < 32) ? det0[di] : h[di - 32];
                    er  = fmaf(sf[k],  ap[k], er);
                    orr = fmaf(wv8[k], dv,    orr);
                }
                const int d0i = p * 16 + j;
                float dvj = (d0i < 32) ? det0[d0i] : h[d0i - 32];
                er  += dvj;                      // even_rest[n]
                orr += ap[0];                    // odd_rest[n]
                if ((j & 1) == 0) { e0 = er; o0 = orr; }
                else *(float4*)(outr + 2 * (n - 1)) = make_float4(e0, o0, er, orr);
                if (j < 15) {
                    #pragma unroll
                    for (int k = 0; k < 7; ++k) ap[k] = ap[k + 1];
                    ap[7] = buf[SW((n + 8) & 32767)];
                }
            }
        }
    }
}

extern "C" void kernel_launch(void* const* d_in, const int* in_sizes, int n_in,
                              void* d_out, int out_size, void* d_ws, size_t ws_size,
                              hipStream_t stream) {
    const float* x           = (const float*)d_in[0];
    const float* scaling     = (const float*)d_in[1];
    const float* scaling_rec = (const float*)d_in[2];
    const float* p_alpha     = (const float*)d_in[3];
    const float* p_bp        = (const float*)d_in[4];
    const float* p_bm        = (const float*)d_in[5];
    float* out = (float*)d_out;

    // zero the loss accumulator each launch (graph-capture safe)
    hipMemsetAsync(out + LOSS_IDX, 0, sizeof(float), stream);

    wavelet_vcycle_kernel<<<dim3(NROWS), dim3(TPB), 32768 * sizeof(float), stream>>>(
        x, scaling, scaling_rec, p_alpha, p_bp, p_bm, out);
}